// Round 7
// baseline (223.041 us; speedup 1.0000x reference)
//
#include <hip/hip_runtime.h>
#include <hip/hip_bf16.h>

// DenseContrastiveLossV2 on MI355X — round 7.
// K0 k_gather : block (b,c) loads feat row coalesced to LDS, scatter-writes
//               raw bf16 straight into F[vec][c] (2B stores, L2-absorbed).
//               No FT, no transpose kernel.
// K1 k_scale  : in-place L2-normalize F rows, coalesced; sumsq computed from
//               bf16 values (error ~2^-8 rel, << bf16-grade threshold);
//               zeroes ns.
// K2 k_neg    : 64 rows x 32-candidate-tile quarter; A frags in regs; B frags
//               SOFTWARE-PIPELINED across tiles with explicit ping-pong
//               register buffers (prefetch tile ii+1 while MFMA-ing tile ii;
//               no dynamic reg indexing -> no scratch). Per-row
//               sum exp(2*dot-2) -> atomicAdd ns[row].
// K3 k_pos    : matching-label tiles, single-buffered (few tiles); sums
//               (d - log(exp d + ns[i])) over i!=j; atomicAdd scalar loss.
//               (shift m=2 cancels exactly in logprob; diag dot/temp == 2)

namespace {

constexpr int kC = 256;
constexpr int kHW = 96 * 96;   // 9216
constexpr int kT = 32;
constexpr int kV = 256;
constexpr int kM = kT * kV;    // 8192

typedef __attribute__((ext_vector_type(8))) short short8;  // 8 bf16
typedef __attribute__((ext_vector_type(4))) float f32x4;

__device__ inline unsigned short f2bf(float x) {
  __hip_bfloat16 h = __float2bfloat16(x);
  return __builtin_bit_cast(unsigned short, h);
}
__device__ inline float bf2f(unsigned short u) {
  unsigned int v = ((unsigned int)u) << 16;
  return __builtin_bit_cast(float, v);
}

}  // namespace

// ---------------- K0: gather -> raw bf16 F[vec][c] ----------------
__global__ __launch_bounds__(256) void k_gather(
    const float* __restrict__ feat, const int* __restrict__ binds,
    const int* __restrict__ sinds, unsigned short* __restrict__ F) {
  const int b = (int)blockIdx.x;   // 0..7
  const int c = (int)blockIdx.y;   // 0..255
  __shared__ alignas(16) float row[kHW];
  __shared__ int s_b[kT];
  const int tid = (int)threadIdx.x;
  if (tid < kT) s_b[tid] = binds[tid];
  __syncthreads();
  bool any = false;
#pragma unroll
  for (int t = 0; t < kT; ++t) any |= (s_b[t] == b);
  if (!any) return;
  const float4* src4 = (const float4*)(feat + ((size_t)b * kC + c) * kHW);
  for (int i = tid; i < kHW / 4; i += 256) ((float4*)row)[i] = src4[i];
  __syncthreads();
  for (int t = 0; t < kT; ++t) {
    if (s_b[t] != b) continue;
    const int p = sinds[t * kV + tid];
    F[(size_t)(t * kV + tid) * kC + c] = f2bf(row[p]);
  }
}

// ---------------- K1: in-place normalize (+ zero ns) ----------------
__global__ __launch_bounds__(256) void k_scale(unsigned short* __restrict__ F,
                                               float* __restrict__ ns) {
  const int tid = (int)threadIdx.x;
  const int v = (int)blockIdx.x * 32 + (tid >> 3);  // 32 rows/block, 8 thr/row
  const int ch = tid & 7;
  if (tid < 32) ns[(int)blockIdx.x * 32 + tid] = 0.f;
  short* rowp = (short*)F + (size_t)v * kC;
  short8 d[4];
#pragma unroll
  for (int s = 0; s < 4; ++s)
    d[s] = *(const short8*)(rowp + (s * 8 + ch) * 8);
  float ss = 0.f;
#pragma unroll
  for (int s = 0; s < 4; ++s)
#pragma unroll
    for (int k = 0; k < 8; ++k) {
      float x = bf2f((unsigned short)d[s][k]);
      ss += x * x;
    }
  ss += __shfl_xor(ss, 1, 64);
  ss += __shfl_xor(ss, 2, 64);
  ss += __shfl_xor(ss, 4, 64);
  const float inv = 1.0f / fmaxf(sqrtf(ss), 1e-12f);
#pragma unroll
  for (int s = 0; s < 4; ++s) {
    short8 o;
#pragma unroll
    for (int k = 0; k < 8; ++k)
      o[k] = (short)f2bf(bf2f((unsigned short)d[s][k]) * inv);
    *(short8*)(rowp + (s * 8 + ch) * 8) = o;
  }
}

// ---------------- K2: negative sweep, pipelined -> ns[row] ----------------
__global__ __launch_bounds__(256, 2) void k_neg(
    const unsigned short* __restrict__ F, const int* __restrict__ labels,
    float* __restrict__ ns) {
  const int tid = (int)threadIdx.x;
  const int w = tid >> 6, lane = tid & 63, q = lane >> 4, l16 = lane & 15;
  const int row0 = (int)blockIdx.y * 64;
  const int cx = (int)blockIdx.x;  // 0..3, 32 candidate tiles each
  __shared__ int s_lab[kT];
  __shared__ int s_list[33];
  __shared__ float s_red[4][64];
  if (tid < kT) s_lab[tid] = labels[tid];
  __syncthreads();
  const int labr = s_lab[row0 >> 8];
  if (tid == 0) {
    int c = 0;
    for (int ct = cx * 32; ct < cx * 32 + 32; ++ct)
      if (s_lab[ct >> 2] != labr) s_list[1 + c++] = ct;
    s_list[0] = c;
  }
  const short* Fs = (const short*)F;

  short8 af[4][8];
#pragma unroll
  for (int rg = 0; rg < 4; ++rg)
#pragma unroll
    for (int ks = 0; ks < 8; ++ks)
      af[rg][ks] = *(const short8*)(Fs + (size_t)(row0 + rg * 16 + l16) * kC +
                                    ks * 32 + q * 8);
  __syncthreads();
  const int cnt = s_list[0];
  const int colbase = w * 16 + l16;

  float sacc[4][4] = {};
  auto bload = [&](int ct, short8* bq) {
    const short* bp = Fs + (size_t)(ct * 64 + colbase) * kC + q * 8;
#pragma unroll
    for (int ks = 0; ks < 8; ++ks) bq[ks] = *(const short8*)(bp + ks * 32);
  };
  auto ctile = [&](short8* bq) {
    f32x4 acc[4];
#pragma unroll
    for (int rg = 0; rg < 4; ++rg) acc[rg] = (f32x4){0.f, 0.f, 0.f, 0.f};
#pragma unroll
    for (int ks = 0; ks < 8; ++ks)
#pragma unroll
      for (int rg = 0; rg < 4; ++rg)
        acc[rg] = __builtin_amdgcn_mfma_f32_16x16x32_bf16(af[rg][ks], bq[ks],
                                                          acc[rg], 0, 0, 0);
#pragma unroll
    for (int rg = 0; rg < 4; ++rg)
#pragma unroll
      for (int r = 0; r < 4; ++r)
        sacc[rg][r] += __expf(fmaf(acc[rg][r], 2.f, -2.f));
  };

  short8 bA[8], bB[8];
  if (cnt > 0) bload(s_list[1], bA);
  int ii = 0;
  while (ii < cnt) {
    if (ii + 1 < cnt) bload(s_list[2 + ii], bB);  // prefetch next into B
    ctile(bA);                                    // compute current from A
    ++ii;
    if (ii >= cnt) break;
    if (ii + 1 < cnt) bload(s_list[2 + ii], bA);  // prefetch next into A
    ctile(bB);                                    // compute current from B
    ++ii;
  }

#pragma unroll
  for (int rg = 0; rg < 4; ++rg)
#pragma unroll
    for (int r = 0; r < 4; ++r) {
      float v = sacc[rg][r];
      v += __shfl_xor(v, 1, 64);
      v += __shfl_xor(v, 2, 64);
      v += __shfl_xor(v, 4, 64);
      v += __shfl_xor(v, 8, 64);
      if (l16 == 0) s_red[w][rg * 16 + q * 4 + r] = v;
    }
  __syncthreads();
  if (tid < 64) {
    float v = s_red[0][tid] + s_red[1][tid] + s_red[2][tid] + s_red[3][tid];
    atomicAdd(&ns[row0 + tid], v);
  }
}

// ---------------- K3: positive sweep -> loss --------------
__global__ __launch_bounds__(256, 2) void k_pos(
    const unsigned short* __restrict__ F, const int* __restrict__ labels,
    const float* __restrict__ ns, float* __restrict__ out) {
  const int tid = (int)threadIdx.x;
  const int w = tid >> 6, lane = tid & 63, q = lane >> 4, l16 = lane & 15;
  const int row0 = (int)blockIdx.y * 64;
  const int cx = (int)blockIdx.x;  // 0..3
  __shared__ int s_lab[kT];
  __shared__ float s_pos[4];
  if (tid < kT) s_lab[tid] = labels[tid];
  __syncthreads();
  const int labr = s_lab[row0 >> 8];
  bool anyp = false;
#pragma unroll
  for (int tq = 0; tq < 8; ++tq) anyp |= (s_lab[cx * 8 + tq] == labr);
  if (!anyp) return;
  const short* Fs = (const short*)F;

  short8 af[4][8];
#pragma unroll
  for (int rg = 0; rg < 4; ++rg)
#pragma unroll
    for (int ks = 0; ks < 8; ++ks)
      af[rg][ks] = *(const short8*)(Fs + (size_t)(row0 + rg * 16 + l16) * kC +
                                    ks * 32 + q * 8);
  float nsv[4][4];
#pragma unroll
  for (int rg = 0; rg < 4; ++rg)
#pragma unroll
    for (int r = 0; r < 4; ++r)
      nsv[rg][r] = ns[row0 + rg * 16 + q * 4 + r];

  const int colbase = w * 16 + l16;
  float pos = 0.f;
  for (int ct = cx * 32; ct < cx * 32 + 32; ++ct) {
    if (s_lab[ct >> 2] != labr) continue;
    const short* bp = Fs + (size_t)(ct * 64 + colbase) * kC + q * 8;
    f32x4 acc[4];
#pragma unroll
    for (int rg = 0; rg < 4; ++rg) acc[rg] = (f32x4){0.f, 0.f, 0.f, 0.f};
#pragma unroll
    for (int ks = 0; ks < 8; ++ks) {
      short8 bf = *(const short8*)(bp + ks * 32);
#pragma unroll
      for (int rg = 0; rg < 4; ++rg)
        acc[rg] = __builtin_amdgcn_mfma_f32_16x16x32_bf16(af[rg][ks], bf,
                                                          acc[rg], 0, 0, 0);
    }
    const int jcol = ct * 64 + colbase;
#pragma unroll
    for (int rg = 0; rg < 4; ++rg)
#pragma unroll
      for (int r = 0; r < 4; ++r) {
        const int i = row0 + rg * 16 + q * 4 + r;
        if (i != jcol) {
          float d = fmaf(acc[rg][r], 2.f, -2.f);
          pos += d - __logf(__expf(d) + nsv[rg][r]);
        }
      }
  }
#pragma unroll
  for (int m = 1; m < 64; m <<= 1) pos += __shfl_xor(pos, m, 64);
  if (lane == 0) s_pos[w] = pos;
  __syncthreads();
  if (tid == 0) {
    float tot = s_pos[0] + s_pos[1] + s_pos[2] + s_pos[3];
    int matches = 0;
    for (int t = 0; t < kT; ++t) matches += (s_lab[t] == labr) ? 1 : 0;
    const float pcnt = (float)(matches * kV - 1);
    atomicAdd(out, -tot / (pcnt * (float)kM));
  }
}

extern "C" void kernel_launch(void* const* d_in, const int* in_sizes, int n_in,
                              void* d_out, int out_size, void* d_ws,
                              size_t ws_size, hipStream_t stream) {
  const float* feat = (const float*)d_in[0];
  const int* binds = (const int*)d_in[1];
  const int* sinds = (const int*)d_in[2];
  const int* labels = (const int*)d_in[3];
  float* out = (float*)d_out;
  unsigned short* F = (unsigned short*)d_ws;             // 4 MB  [8192][256]
  float* ns = (float*)(F + (size_t)kM * kC);             // 32 KB [8192]

  hipMemsetAsync(d_out, 0, sizeof(float) * out_size, stream);
  k_gather<<<dim3(8, kC), 256, 0, stream>>>(feat, binds, sinds, F);
  k_scale<<<kM / 32, 256, 0, stream>>>(F, ns);
  k_neg<<<dim3(4, kM / 64), 256, 0, stream>>>(F, labels, ns);
  k_pos<<<dim3(4, kM / 64), 256, 0, stream>>>(F, labels, ns, out);
}